// Round 3
// baseline (834.198 us; speedup 1.0000x reference)
//
#include <hip/hip_runtime.h>
#include <math.h>

#define NN 50000
#define NE 600000
// D = H = 128 hard-coded. NE % 32 == 0 (18750 edge tiles, no tail).

typedef __attribute__((ext_vector_type(8))) short bf16x8;
typedef __attribute__((ext_vector_type(4))) float f32x4;

__device__ __forceinline__ float silu_f(float x) {
    return x / (1.0f + __expf(-x));
}
__device__ __forceinline__ unsigned short f2bf(float x) {
    unsigned int u = __float_as_uint(x);
    return (unsigned short)((u + 0x7FFFu + ((u >> 16) & 1u)) >> 16);
}
__device__ __forceinline__ float bf2f(unsigned short s) {
    return __uint_as_float(((unsigned int)s) << 16);
}

// ---------------- counting sort of edges by row --------------------------
__global__ __launch_bounds__(256) void hist_kernel(
    const int* __restrict__ erow, int* __restrict__ bins) {
    int i = blockIdx.x * 256 + threadIdx.x;
    if (i < NE) atomicAdd(&bins[erow[i]], 1);
}

__global__ __launch_bounds__(256) void scan1_kernel(
    const int* __restrict__ bins, int* __restrict__ bsum) {
    int gid = blockIdx.x * 256 + threadIdx.x;
    int v = (gid < NN) ? bins[gid] : 0;
    int lane = threadIdx.x & 63, wave = threadIdx.x >> 6;
#pragma unroll
    for (int d = 1; d < 64; d <<= 1) {
        int n = __shfl_up(v, d);
        if (lane >= d) v += n;
    }
    __shared__ int wsum[4];
    if (lane == 63) wsum[wave] = v;
    __syncthreads();
    if (threadIdx.x == 255) {
        // v currently inclusive of last wave; total = sum of wave sums
        bsum[blockIdx.x] = wsum[0] + wsum[1] + wsum[2] + wsum[3];
    }
}

__global__ void scan2_kernel(int* bsum, int nb) {
    if (threadIdx.x == 0 && blockIdx.x == 0) {
        int acc = 0;
        for (int i = 0; i < nb; i++) { int t = bsum[i]; bsum[i] = acc; acc += t; }
    }
}

__global__ __launch_bounds__(256) void scan3_kernel(
    const int* __restrict__ bins, const int* __restrict__ bsum,
    int* __restrict__ cur) {
    int gid = blockIdx.x * 256 + threadIdx.x;
    int v = (gid < NN) ? bins[gid] : 0;
    int lane = threadIdx.x & 63, wave = threadIdx.x >> 6;
    int inc = v;
#pragma unroll
    for (int d = 1; d < 64; d <<= 1) {
        int n = __shfl_up(inc, d);
        if (lane >= d) inc += n;
    }
    __shared__ int wsum[4];
    if (lane == 63) wsum[wave] = inc;
    __syncthreads();
    int wadd = 0;
    for (int w = 0; w < wave; w++) wadd += wsum[w];
    if (gid < NN) cur[gid] = bsum[blockIdx.x] + wadd + inc - v;  // exclusive
}

__global__ __launch_bounds__(256) void scatter_kernel(
    const int* __restrict__ erow, int* __restrict__ cur,
    int* __restrict__ perm) {
    int i = blockIdx.x * 256 + threadIdx.x;
    if (i < NE) {
        int r = erow[i];
        int pos = atomicAdd(&cur[r], 1);
        perm[pos] = i;
    }
}

// ---------------- weight transpose+cast to bf16 --------------------------
__global__ __launch_bounds__(256) void prep_weights(
    const float* __restrict__ w1, const float* __restrict__ w2,
    const float* __restrict__ cw1, const float* __restrict__ nw1,
    const float* __restrict__ nw2,
    unsigned short* __restrict__ w1T, unsigned short* __restrict__ w2T,
    unsigned short* __restrict__ cw1T, unsigned short* __restrict__ nw1T,
    unsigned short* __restrict__ nw2T) {
    int i = blockIdx.x * 256 + threadIdx.x;
    if (i < 32768) { int n = i >> 8, k = i & 255; w1T[i] = f2bf(w1[k * 128 + n]); return; }
    int j = i - 32768;
    if (j < 16384) { int n = j >> 7, k = j & 127; w2T[j] = f2bf(w2[k * 128 + n]); return; }
    j -= 16384;
    if (j < 16384) { int n = j >> 7, k = j & 127; cw1T[j] = f2bf(cw1[k * 128 + n]); return; }
    j -= 16384;
    if (j < 32768) { int n = j >> 8, k = j & 255; nw1T[j] = f2bf(nw1[k * 128 + n]); return; }
    j -= 32768;
    if (j < 16384) { int n = j >> 7, k = j & 127; nw2T[j] = f2bf(nw2[k * 128 + n]); return; }
}

// ---------------- node LayerNorm -> hn (bf16) ----------------------------
__global__ __launch_bounds__(256) void ln_nodes_kernel(
    const float* __restrict__ h, const float* __restrict__ g,
    const float* __restrict__ b, unsigned short* __restrict__ hnb) {
    int node = blockIdx.x * 4 + (threadIdx.x >> 6);
    int lane = threadIdx.x & 63;
    if (node >= NN) return;
    const float* row = h + (size_t)node * 128;
    float x0 = row[lane], x1 = row[lane + 64];
    float s = x0 + x1, s2 = x0 * x0 + x1 * x1;
#pragma unroll
    for (int off = 32; off; off >>= 1) {
        s  += __shfl_xor(s, off);
        s2 += __shfl_xor(s2, off);
    }
    float m = s * (1.0f / 128.0f);
    float v = s2 * (1.0f / 128.0f) - m * m;
    float inv = rsqrtf(v + 1e-5f);
    unsigned short* orow = hnb + (size_t)node * 128;
    orow[lane]      = f2bf((x0 - m) * inv * g[lane]      + b[lane]);
    orow[lane + 64] = f2bf((x1 - m) * inv * g[lane + 64] + b[lane + 64]);
}

// swizzled ushort index into a [rows][128] bf16 LDS tile (16B chunk XOR)
__device__ __forceinline__ int swz128(int row, int col) {
    return row * 128 + (((col >> 3) ^ (row & 7)) << 3) + (col & 7);
}

// ---------------- fused MFMA edge kernel (sorted edges) ------------------
// 256 threads = 4 waves; wave w owns output features [w*32, w*32+32).
// Each block owns a CONTIGUOUS range of 32-edge tiles; blocks are mapped so
// each XCD (blockIdx%8) gets a contiguous 1/8 of the edge list -> its agg
// atomic window (~3.2 MB) stays L2-resident.
#define NTILES (NE / 32)
#define PER_XCD 2344          // ceil(18750/8)
#define TPB 19                // ceil(2344/128)
__global__ __launch_bounds__(256, 2) void edge_kernel(
    const unsigned short* __restrict__ hnb,
    const int* __restrict__ erow, const int* __restrict__ ecol,
    const int* __restrict__ perm,
    const float* __restrict__ coord,
    const float* __restrict__ eg, const float* __restrict__ ebias,
    const float* __restrict__ w1, const float* __restrict__ b1,
    const float* __restrict__ b2, const float* __restrict__ cb1,
    const float* __restrict__ cw2,
    const unsigned short* __restrict__ w1T,
    const unsigned short* __restrict__ w2T,
    const unsigned short* __restrict__ cw1T,
    float* __restrict__ agg, float* __restrict__ svec) {
    __shared__ uint4 a1s[32 * 32];   // 16 KB: A1 tile [32 edges][256 k] bf16, swizzled
    __shared__ uint4 e1s[32 * 16];   //  8 KB: e1 then post-LN e [32][128] bf16
    __shared__ uint4 e2s[32 * 16];   //  8 KB: e2 (pre-LN)
    __shared__ float cdS[32][3];
    __shared__ float radS[32];
    __shared__ float scalef[32];
    __shared__ int   rids[32], cids[32];

    const int t    = threadIdx.x;
    const int lane = t & 63;
    const int wave = t >> 6;
    const int l15  = lane & 15;
    const int g4   = lane >> 4;
    const int n0   = wave * 32;
    const int sw   = l15 & 7;

    // ---- preload weight fragments (B^T rows, contiguous K per lane) ----
    bf16x8 B1[2][8], B2[2][4], B3[2][4];
    float b1v[2], b2v[2], cb1v[2], cw2v[2], w1rv[2];
#pragma unroll
    for (int nf = 0; nf < 2; nf++) {
        int wr = n0 + nf * 16 + l15;          // output feature / B^T row
        const unsigned short* p1 = w1T + wr * 256 + g4 * 8;
#pragma unroll
        for (int kc = 0; kc < 8; kc++) B1[nf][kc] = *(const bf16x8*)(p1 + kc * 32);
        const unsigned short* p2 = w2T + wr * 128 + g4 * 8;
#pragma unroll
        for (int kc = 0; kc < 4; kc++) B2[nf][kc] = *(const bf16x8*)(p2 + kc * 32);
        const unsigned short* p3 = cw1T + wr * 128 + g4 * 8;
#pragma unroll
        for (int kc = 0; kc < 4; kc++) B3[nf][kc] = *(const bf16x8*)(p3 + kc * 32);
        b1v[nf]  = b1[wr];  b2v[nf] = b2[wr];
        cb1v[nf] = cb1[wr]; cw2v[nf] = cw2[wr];
        w1rv[nf] = w1[256 * 128 + wr];        // radial row of w1 (fp32)
    }
    const float egl0 = eg[lane],   egl1 = eg[lane + 64];
    const float ebl0 = ebias[lane], ebl1 = ebias[lane + 64];

    unsigned short* e1u = (unsigned short*)e1s;
    unsigned short* e2u = (unsigned short*)e2s;

    const int xcd = blockIdx.x & 7;
    const int bi  = blockIdx.x >> 3;
    int t0 = xcd * PER_XCD + bi * TPB;
    int tcap = xcd * PER_XCD + PER_XCD; if (tcap > NTILES) tcap = NTILES;
    int t1 = t0 + TPB; if (t1 > tcap) t1 = tcap;

    for (int tile = t0; tile < t1; tile++) {
        const int e0 = tile * 32;
        __syncthreads();   // previous tile fully consumed (incl. trans scatter)
        if (t < 32) {
            int eid = perm[e0 + t];
            int r = erow[eid], c = ecol[eid];
            rids[t] = r; cids[t] = c;
            float dx = coord[r * 3 + 0] - coord[c * 3 + 0];
            float dy = coord[r * 3 + 1] - coord[c * 3 + 1];
            float dz = coord[r * 3 + 2] - coord[c * 3 + 2];
            cdS[t][0] = dx; cdS[t][1] = dy; cdS[t][2] = dz;
            radS[t] = dx * dx + dy * dy + dz * dz;
            scalef[t] = 0.0f;
        }
        __syncthreads();   // ids ready for staging
        // stage A1 = [hn[row] | hn[col]] as bf16, 16B chunks, swizzled
#pragma unroll
        for (int ii = 0; ii < 4; ii++) {
            int idx = t + ii * 256;
            int rr = idx >> 5, c = idx & 31;
            int nd = (c < 16) ? rids[rr] : cids[rr];
            int cc = c & 15;
            uint4 d = *(const uint4*)(hnb + (size_t)nd * 128 + cc * 8);
            a1s[rr * 32 + (c ^ (rr & 7))] = d;
        }
        __syncthreads();

        // ---- GEMM1: e1 = silu(A1 @ w1[:256] + radial*w1r + b1) ----
        f32x4 a00 = {0,0,0,0}, a01 = {0,0,0,0}, a10 = {0,0,0,0}, a11 = {0,0,0,0};
        {
            const bf16x8* A = (const bf16x8*)a1s;
#pragma unroll
            for (int kc = 0; kc < 8; kc++) {
                int ch = kc * 4 + g4;
                bf16x8 f0 = A[l15 * 32 + (ch ^ sw)];
                bf16x8 f1 = A[(l15 + 16) * 32 + (ch ^ sw)];
                a00 = __builtin_amdgcn_mfma_f32_16x16x32_bf16(f0, B1[0][kc], a00, 0, 0, 0);
                a01 = __builtin_amdgcn_mfma_f32_16x16x32_bf16(f0, B1[1][kc], a01, 0, 0, 0);
                a10 = __builtin_amdgcn_mfma_f32_16x16x32_bf16(f1, B1[0][kc], a10, 0, 0, 0);
                a11 = __builtin_amdgcn_mfma_f32_16x16x32_bf16(f1, B1[1][kc], a11, 0, 0, 0);
            }
        }
#pragma unroll
        for (int mf = 0; mf < 2; mf++) {
#pragma unroll
            for (int r = 0; r < 4; r++) {
                int row = mf * 16 + g4 * 4 + r;
                float rad = radS[row];
#pragma unroll
                for (int nf = 0; nf < 2; nf++) {
                    float v = mf ? (nf ? a11[r] : a10[r]) : (nf ? a01[r] : a00[r]);
                    v = silu_f(v + rad * w1rv[nf] + b1v[nf]);
                    int col = n0 + nf * 16 + l15;
                    e1u[swz128(row, col)] = f2bf(v);
                }
            }
        }
        __syncthreads();

        // ---- GEMM2: e2 = silu(e1 @ w2 + b2) ----
        f32x4 c00 = {0,0,0,0}, c01 = {0,0,0,0}, c10 = {0,0,0,0}, c11 = {0,0,0,0};
        {
            const bf16x8* A = (const bf16x8*)e1s;
#pragma unroll
            for (int kc = 0; kc < 4; kc++) {
                int ch = kc * 4 + g4;
                bf16x8 f0 = A[l15 * 16 + (ch ^ sw)];
                bf16x8 f1 = A[(l15 + 16) * 16 + (ch ^ sw)];
                c00 = __builtin_amdgcn_mfma_f32_16x16x32_bf16(f0, B2[0][kc], c00, 0, 0, 0);
                c01 = __builtin_amdgcn_mfma_f32_16x16x32_bf16(f0, B2[1][kc], c01, 0, 0, 0);
                c10 = __builtin_amdgcn_mfma_f32_16x16x32_bf16(f1, B2[0][kc], c10, 0, 0, 0);
                c11 = __builtin_amdgcn_mfma_f32_16x16x32_bf16(f1, B2[1][kc], c11, 0, 0, 0);
            }
        }
#pragma unroll
        for (int mf = 0; mf < 2; mf++) {
#pragma unroll
            for (int r = 0; r < 4; r++) {
                int row = mf * 16 + g4 * 4 + r;
#pragma unroll
                for (int nf = 0; nf < 2; nf++) {
                    float v = mf ? (nf ? c11[r] : c10[r]) : (nf ? c01[r] : c00[r]);
                    v = silu_f(v + b2v[nf]);
                    int col = n0 + nf * 16 + l15;
                    e2u[swz128(row, col)] = f2bf(v);
                }
            }
        }
        __syncthreads();

        // ---- edge LayerNorm + SEGMENT-COMBINED agg scatter; e -> e1s ----
        {
            float accY0 = 0.0f, accY1 = 0.0f;
            int curRow = rids[wave * 8];
#pragma unroll
            for (int i = 0; i < 8; i++) {
                int e = wave * 8 + i;
                float x0 = bf2f(e2u[swz128(e, lane)]);
                float x1 = bf2f(e2u[swz128(e, lane + 64)]);
                float s = x0 + x1, s2 = x0 * x0 + x1 * x1;
#pragma unroll
                for (int off = 32; off; off >>= 1) {
                    s  += __shfl_xor(s, off);
                    s2 += __shfl_xor(s2, off);
                }
                float m = s * (1.0f / 128.0f);
                float va = s2 * (1.0f / 128.0f) - m * m;
                float inv = rsqrtf(va + 1e-5f);
                float y0 = (x0 - m) * inv * egl0 + ebl0;
                float y1 = (x1 - m) * inv * egl1 + ebl1;
                e1u[swz128(e, lane)]      = f2bf(y0);
                e1u[swz128(e, lane + 64)] = f2bf(y1);
                int r = rids[e];                    // wave-uniform
                if (r != curRow) {
                    atomicAdd(&agg[(size_t)curRow * 128 + lane], accY0);
                    atomicAdd(&agg[(size_t)curRow * 128 + lane + 64], accY1);
                    accY0 = 0.0f; accY1 = 0.0f; curRow = r;
                }
                accY0 += y0; accY1 += y1;
            }
            atomicAdd(&agg[(size_t)curRow * 128 + lane], accY0);
            atomicAdd(&agg[(size_t)curRow * 128 + lane + 64], accY1);
        }
        __syncthreads();

        // ---- GEMM3: p = silu(e @ cw1 + cb1) * cw2 ; scale = row-sum p ----
        f32x4 d00 = {0,0,0,0}, d01 = {0,0,0,0}, d10 = {0,0,0,0}, d11 = {0,0,0,0};
        {
            const bf16x8* A = (const bf16x8*)e1s;
#pragma unroll
            for (int kc = 0; kc < 4; kc++) {
                int ch = kc * 4 + g4;
                bf16x8 f0 = A[l15 * 16 + (ch ^ sw)];
                bf16x8 f1 = A[(l15 + 16) * 16 + (ch ^ sw)];
                d00 = __builtin_amdgcn_mfma_f32_16x16x32_bf16(f0, B3[0][kc], d00, 0, 0, 0);
                d01 = __builtin_amdgcn_mfma_f32_16x16x32_bf16(f0, B3[1][kc], d01, 0, 0, 0);
                d10 = __builtin_amdgcn_mfma_f32_16x16x32_bf16(f1, B3[0][kc], d10, 0, 0, 0);
                d11 = __builtin_amdgcn_mfma_f32_16x16x32_bf16(f1, B3[1][kc], d11, 0, 0, 0);
            }
        }
        {
            float prow[2][4];
#pragma unroll
            for (int mf = 0; mf < 2; mf++)
#pragma unroll
                for (int r = 0; r < 4; r++) prow[mf][r] = 0.0f;
#pragma unroll
            for (int mf = 0; mf < 2; mf++)
#pragma unroll
                for (int r = 0; r < 4; r++)
#pragma unroll
                    for (int nf = 0; nf < 2; nf++) {
                        float v = mf ? (nf ? d11[r] : d10[r]) : (nf ? d01[r] : d00[r]);
                        prow[mf][r] += silu_f(v + cb1v[nf]) * cw2v[nf];
                    }
#pragma unroll
            for (int mf = 0; mf < 2; mf++)
#pragma unroll
                for (int r = 0; r < 4; r++) {
                    float v = prow[mf][r];
                    v += __shfl_xor(v, 1); v += __shfl_xor(v, 2);
                    v += __shfl_xor(v, 4); v += __shfl_xor(v, 8);
                    if (l15 == 0) atomicAdd(&scalef[mf * 16 + g4 * 4 + r], v);
                }
        }
        __syncthreads();

        // ---- segment-combined trans scatter (rows sorted within tile) ----
        if (t < 3) {
            int j = t;
            float acc = 0.0f;
            int curRow = rids[0];
            for (int e = 0; e < 32; e++) {
                int r = rids[e];
                if (r != curRow) {
                    atomicAdd(&svec[curRow * 3 + j], acc);
                    acc = 0.0f; curRow = r;
                }
                acc += cdS[e][j] * scalef[e];
            }
            atomicAdd(&svec[curRow * 3 + j], acc);
        }
    }
}

// ---------------- MFMA node kernel + coord_out ---------------------------
__global__ __launch_bounds__(256, 2) void node_kernel(
    const float* __restrict__ h, const unsigned short* __restrict__ hnb,
    const float* __restrict__ aggp, const float* __restrict__ coord,
    const float* __restrict__ nb1, const float* __restrict__ nb2,
    const unsigned short* __restrict__ nw1T,
    const unsigned short* __restrict__ nw2T,
    const float* __restrict__ svec, const int* __restrict__ bins,
    float* __restrict__ hout, float* __restrict__ cout) {
    __shared__ uint4 a1s[32 * 32];   // [32 nodes][256 k] bf16, swizzled
    __shared__ uint4 nbs[32 * 16];   // hidden [32][128] bf16

    const int t    = threadIdx.x;
    const int lane = t & 63;
    const int wave = t >> 6;
    const int l15  = lane & 15;
    const int g4   = lane >> 4;
    const int n0   = wave * 32;
    const int sw   = l15 & 7;

    bf16x8 B1[2][8], B2[2][4];
    float nb1v[2], nb2v[2];
#pragma unroll
    for (int nf = 0; nf < 2; nf++) {
        int wr = n0 + nf * 16 + l15;
        const unsigned short* p1 = nw1T + wr * 256 + g4 * 8;
#pragma unroll
        for (int kc = 0; kc < 8; kc++) B1[nf][kc] = *(const bf16x8*)(p1 + kc * 32);
        const unsigned short* p2 = nw2T + wr * 128 + g4 * 8;
#pragma unroll
        for (int kc = 0; kc < 4; kc++) B2[nf][kc] = *(const bf16x8*)(p2 + kc * 32);
        nb1v[nf] = nb1[wr]; nb2v[nf] = nb2[wr];
    }
    unsigned short* nbu = (unsigned short*)nbs;

    const int NT = (NN + 31) / 32;
    for (int tile = blockIdx.x; tile < NT; tile += gridDim.x) {
        const int n0t = tile * 32;
        int nn = NN - n0t; if (nn > 32) nn = 32;

        // coord_out (independent of LDS state)
        if (t < 96) {
            int i = t / 3, j = t - (t / 3) * 3;
            int node = n0t + i;
            if (i < nn) {
                float c = fmaxf((float)bins[node], 1.0f);
                cout[node * 3 + j] = coord[node * 3 + j] + svec[node * 3 + j] / c;
            }
        }
        __syncthreads();
        // stage A = [hn (bf16) | agg (fp32->bf16)]
#pragma unroll
        for (int ii = 0; ii < 4; ii++) {
            int idx = t + ii * 256;
            int rr = idx >> 5, c = idx & 31;
            int node = n0t + ((rr < nn) ? rr : 0);
            uint4 d;
            if (c < 16) {
                d = *(const uint4*)(hnb + (size_t)node * 128 + c * 8);
            } else {
                const float* ap = aggp + (size_t)node * 128 + (c - 16) * 8;
                float4 f0 = *(const float4*)ap;
                float4 f1 = *(const float4*)(ap + 4);
                d.x = f2bf(f0.x) | ((unsigned)f2bf(f0.y) << 16);
                d.y = f2bf(f0.z) | ((unsigned)f2bf(f0.w) << 16);
                d.z = f2bf(f1.x) | ((unsigned)f2bf(f1.y) << 16);
                d.w = f2bf(f1.z) | ((unsigned)f2bf(f1.w) << 16);
            }
            a1s[rr * 32 + (c ^ (rr & 7))] = d;
        }
        __syncthreads();

        f32x4 a00 = {0,0,0,0}, a01 = {0,0,0,0}, a10 = {0,0,0,0}, a11 = {0,0,0,0};
        {
            const bf16x8* A = (const bf16x8*)a1s;
#pragma unroll
            for (int kc = 0; kc < 8; kc++) {
                int ch = kc * 4 + g4;
                bf16x8 f0 = A[l15 * 32 + (ch ^ sw)];
                bf16x8 f1 = A[(l15 + 16) * 32 + (ch ^ sw)];
                a00 = __builtin_amdgcn_mfma_f32_16x16x32_bf16(f0, B1[0][kc], a00, 0, 0, 0);
                a01 = __builtin_amdgcn_mfma_f32_16x16x32_bf16(f0, B1[1][kc], a01, 0, 0, 0);
                a10 = __builtin_amdgcn_mfma_f32_16x16x32_bf16(f1, B1[0][kc], a10, 0, 0, 0);
                a11 = __builtin_amdgcn_mfma_f32_16x16x32_bf16(f1, B1[1][kc], a11, 0, 0, 0);
            }
        }
#pragma unroll
        for (int mf = 0; mf < 2; mf++) {
#pragma unroll
            for (int r = 0; r < 4; r++) {
                int row = mf * 16 + g4 * 4 + r;
#pragma unroll
                for (int nf = 0; nf < 2; nf++) {
                    float v = mf ? (nf ? a11[r] : a10[r]) : (nf ? a01[r] : a00[r]);
                    v = silu_f(v + nb1v[nf]);
                    int col = n0 + nf * 16 + l15;
                    nbu[swz128(row, col)] = f2bf(v);
                }
            }
        }
        __syncthreads();

        f32x4 c00 = {0,0,0,0}, c01 = {0,0,0,0}, c10 = {0,0,0,0}, c11 = {0,0,0,0};
        {
            const bf16x8* A = (const bf16x8*)nbs;
#pragma unroll
            for (int kc = 0; kc < 4; kc++) {
                int ch = kc * 4 + g4;
                bf16x8 f0 = A[l15 * 16 + (ch ^ sw)];
                bf16x8 f1 = A[(l15 + 16) * 16 + (ch ^ sw)];
                c00 = __builtin_amdgcn_mfma_f32_16x16x32_bf16(f0, B2[0][kc], c00, 0, 0, 0);
                c01 = __builtin_amdgcn_mfma_f32_16x16x32_bf16(f0, B2[1][kc], c01, 0, 0, 0);
                c10 = __builtin_amdgcn_mfma_f32_16x16x32_bf16(f1, B2[0][kc], c10, 0, 0, 0);
                c11 = __builtin_amdgcn_mfma_f32_16x16x32_bf16(f1, B2[1][kc], c11, 0, 0, 0);
            }
        }
#pragma unroll
        for (int mf = 0; mf < 2; mf++) {
#pragma unroll
            for (int r = 0; r < 4; r++) {
                int row = mf * 16 + g4 * 4 + r;
                if (row < nn) {
                    int node = n0t + row;
#pragma unroll
                    for (int nf = 0; nf < 2; nf++) {
                        float v = mf ? (nf ? c11[r] : c10[r]) : (nf ? c01[r] : c00[r]);
                        int col = n0 + nf * 16 + l15;
                        hout[(size_t)node * 128 + col] =
                            v + nb2v[nf] + h[(size_t)node * 128 + col];
                    }
                }
            }
        }
    }
}

extern "C" void kernel_launch(void* const* d_in, const int* in_sizes, int n_in,
                              void* d_out, int out_size, void* d_ws, size_t ws_size,
                              hipStream_t stream) {
    const float* h     = (const float*)d_in[0];
    const int*   eidx  = (const int*)d_in[1];
    const float* coord = (const float*)d_in[2];
    const float* nlg   = (const float*)d_in[3];
    const float* nlb   = (const float*)d_in[4];
    const float* elg   = (const float*)d_in[5];
    const float* elb   = (const float*)d_in[6];
    const float* ew1   = (const float*)d_in[7];
    const float* eb1   = (const float*)d_in[8];
    const float* ew2   = (const float*)d_in[9];
    const float* eb2   = (const float*)d_in[10];
    const float* nw1   = (const float*)d_in[11];
    const float* nb1   = (const float*)d_in[12];
    const float* nw2   = (const float*)d_in[13];
    const float* nb2   = (const float*)d_in[14];
    const float* cw1   = (const float*)d_in[15];
    const float* cb1   = (const float*)d_in[16];
    const float* cw2   = (const float*)d_in[17];

    float* hout = (float*)d_out;
    float* cout = (float*)d_out + (size_t)NN * 128;

    // ws layout (bytes, 16B-aligned):
    char* ws = (char*)d_ws;
    unsigned short* hnb  = (unsigned short*)(ws);             // 12,800,000
    float*          agg  = (float*)(ws + 12800000);           // 25,600,000
    float*          svec = (float*)(ws + 38400000);           //    600,000
    int*            bins = (int*)(ws + 39000000);             //    200,000
    int*            cur  = (int*)(ws + 39200000);             //    200,000
    int*            bsum = (int*)(ws + 39400000);             //      1,024
    int*            perm = (int*)(ws + 39401024);             //  2,400,000
    unsigned short* w1T  = (unsigned short*)(ws + 41801024);  //     65,536
    unsigned short* w2T  = (unsigned short*)(ws + 41866560);  //     32,768
    unsigned short* cw1T = (unsigned short*)(ws + 41899328);  //     32,768
    unsigned short* nw1T = (unsigned short*)(ws + 41932096);  //     65,536
    unsigned short* nw2T = (unsigned short*)(ws + 41997632);  //     32,768

    // zero agg|svec|bins (contiguous region)
    hipMemsetAsync(agg, 0, (size_t)25600000 + 600000 + 200000, stream);

    const int* erow = eidx;
    const int* ecol = eidx + NE;

    const int NB = (NN + 255) / 256;   // 196

    hist_kernel<<<(NE + 255) / 256, 256, 0, stream>>>(erow, bins);
    scan1_kernel<<<NB, 256, 0, stream>>>(bins, bsum);
    scan2_kernel<<<1, 64, 0, stream>>>(bsum, NB);
    scan3_kernel<<<NB, 256, 0, stream>>>(bins, bsum, cur);
    scatter_kernel<<<(NE + 255) / 256, 256, 0, stream>>>(erow, cur, perm);

    prep_weights<<<448, 256, 0, stream>>>(ew1, ew2, cw1, nw1, nw2,
                                          w1T, w2T, cw1T, nw1T, nw2T);
    ln_nodes_kernel<<<(NN + 3) / 4, 256, 0, stream>>>(h, nlg, nlb, hnb);
    edge_kernel<<<1024, 256, 0, stream>>>(
        hnb, erow, ecol, perm, coord, elg, elb, ew1, eb1, eb2, cb1, cw2,
        w1T, w2T, cw1T, agg, svec);
    node_kernel<<<512, 256, 0, stream>>>(
        h, hnb, agg, coord, nb1, nb2, nw1T, nw2T, svec, bins, hout, cout);
}

// Round 4
// 531.408 us; speedup vs baseline: 1.5698x; 1.5698x over previous
//
#include <hip/hip_runtime.h>
#include <math.h>

#define NN 50000
#define NE 600000
// D = H = 128 hard-coded. NE % 16 == 0 (37500 wave-tiles, no tail).

typedef __attribute__((ext_vector_type(8))) short bf16x8;
typedef __attribute__((ext_vector_type(4))) float f32x4;

__device__ __forceinline__ float silu_f(float x) {
    return x / (1.0f + __expf(-x));
}
__device__ __forceinline__ unsigned short f2bf(float x) {
    unsigned int u = __float_as_uint(x);
    return (unsigned short)((u + 0x7FFFu + ((u >> 16) & 1u)) >> 16);
}
__device__ __forceinline__ float bf2f(unsigned short s) {
    return __uint_as_float(((unsigned int)s) << 16);
}

// ---------------- counting sort of edges by row --------------------------
__global__ __launch_bounds__(256) void hist_kernel(
    const int* __restrict__ erow, int* __restrict__ bins) {
    int i = blockIdx.x * 256 + threadIdx.x;
    if (i < NE) atomicAdd(&bins[erow[i]], 1);
}

__global__ __launch_bounds__(256) void scan1_kernel(
    const int* __restrict__ bins, int* __restrict__ bsum) {
    int gid = blockIdx.x * 256 + threadIdx.x;
    int v = (gid < NN) ? bins[gid] : 0;
    int lane = threadIdx.x & 63, wave = threadIdx.x >> 6;
#pragma unroll
    for (int d = 1; d < 64; d <<= 1) {
        int n = __shfl_up(v, d);
        if (lane >= d) v += n;
    }
    __shared__ int wsum[4];
    if (lane == 63) wsum[wave] = v;
    __syncthreads();
    if (threadIdx.x == 255) {
        bsum[blockIdx.x] = wsum[0] + wsum[1] + wsum[2] + wsum[3];
    }
}

__global__ void scan2_kernel(int* bsum, int nb) {
    if (threadIdx.x == 0 && blockIdx.x == 0) {
        int acc = 0;
        for (int i = 0; i < nb; i++) { int t = bsum[i]; bsum[i] = acc; acc += t; }
    }
}

__global__ __launch_bounds__(256) void scan3_kernel(
    const int* __restrict__ bins, const int* __restrict__ bsum,
    int* __restrict__ cur) {
    int gid = blockIdx.x * 256 + threadIdx.x;
    int v = (gid < NN) ? bins[gid] : 0;
    int lane = threadIdx.x & 63, wave = threadIdx.x >> 6;
    int inc = v;
#pragma unroll
    for (int d = 1; d < 64; d <<= 1) {
        int n = __shfl_up(inc, d);
        if (lane >= d) inc += n;
    }
    __shared__ int wsum[4];
    if (lane == 63) wsum[wave] = inc;
    __syncthreads();
    int wadd = 0;
    for (int w = 0; w < wave; w++) wadd += wsum[w];
    if (gid < NN) cur[gid] = bsum[blockIdx.x] + wadd + inc - v;  // exclusive
}

__global__ __launch_bounds__(256) void scatter_kernel(
    const int* __restrict__ erow, int* __restrict__ cur,
    int* __restrict__ perm) {
    int i = blockIdx.x * 256 + threadIdx.x;
    if (i < NE) {
        int r = erow[i];
        int pos = atomicAdd(&cur[r], 1);
        perm[pos] = i;
    }
}

// ---------------- weight transpose+cast to bf16 --------------------------
__global__ __launch_bounds__(256) void prep_weights(
    const float* __restrict__ w1, const float* __restrict__ w2,
    const float* __restrict__ cw1, const float* __restrict__ nw1,
    const float* __restrict__ nw2,
    unsigned short* __restrict__ w1T, unsigned short* __restrict__ w2T,
    unsigned short* __restrict__ cw1T, unsigned short* __restrict__ nw1T,
    unsigned short* __restrict__ nw2T) {
    int i = blockIdx.x * 256 + threadIdx.x;
    if (i < 32768) { int n = i >> 8, k = i & 255; w1T[i] = f2bf(w1[k * 128 + n]); return; }
    int j = i - 32768;
    if (j < 16384) { int n = j >> 7, k = j & 127; w2T[j] = f2bf(w2[k * 128 + n]); return; }
    j -= 16384;
    if (j < 16384) { int n = j >> 7, k = j & 127; cw1T[j] = f2bf(cw1[k * 128 + n]); return; }
    j -= 16384;
    if (j < 32768) { int n = j >> 8, k = j & 255; nw1T[j] = f2bf(nw1[k * 128 + n]); return; }
    j -= 32768;
    if (j < 16384) { int n = j >> 7, k = j & 127; nw2T[j] = f2bf(nw2[k * 128 + n]); return; }
}

// ---------------- node LayerNorm -> hn (bf16) ----------------------------
__global__ __launch_bounds__(256) void ln_nodes_kernel(
    const float* __restrict__ h, const float* __restrict__ g,
    const float* __restrict__ b, unsigned short* __restrict__ hnb) {
    int node = blockIdx.x * 4 + (threadIdx.x >> 6);
    int lane = threadIdx.x & 63;
    if (node >= NN) return;
    const float* row = h + (size_t)node * 128;
    float x0 = row[lane], x1 = row[lane + 64];
    float s = x0 + x1, s2 = x0 * x0 + x1 * x1;
#pragma unroll
    for (int off = 32; off; off >>= 1) {
        s  += __shfl_xor(s, off);
        s2 += __shfl_xor(s2, off);
    }
    float m = s * (1.0f / 128.0f);
    float v = s2 * (1.0f / 128.0f) - m * m;
    float inv = rsqrtf(v + 1e-5f);
    unsigned short* orow = hnb + (size_t)node * 128;
    orow[lane]      = f2bf((x0 - m) * inv * g[lane]      + b[lane]);
    orow[lane + 64] = f2bf((x1 - m) * inv * g[lane + 64] + b[lane + 64]);
}

// ---------------- z precompute: zrow = hn@W_top + b1, zcol = hn@W_bot ----
__global__ __launch_bounds__(256, 2) void z_kernel(
    const unsigned short* __restrict__ hnb,
    const unsigned short* __restrict__ w1T,
    const float* __restrict__ b1,
    unsigned short* __restrict__ zrow, unsigned short* __restrict__ zcol) {
    __shared__ uint4 a1s[32 * 16];   // [32 nodes][128 k] bf16, swizzled

    const int t    = threadIdx.x;
    const int lane = t & 63;
    const int wave = t >> 6;
    const int l15  = lane & 15;
    const int g4   = lane >> 4;
    const int n0   = wave * 32;
    const int sw   = l15 & 7;

    bf16x8 Btop[2][4], Bbot[2][4];
    float b1v[2];
#pragma unroll
    for (int nf = 0; nf < 2; nf++) {
        int wr = n0 + nf * 16 + l15;
        const unsigned short* p1 = w1T + wr * 256 + g4 * 8;
#pragma unroll
        for (int kc = 0; kc < 4; kc++) {
            Btop[nf][kc] = *(const bf16x8*)(p1 + kc * 32);
            Bbot[nf][kc] = *(const bf16x8*)(p1 + 128 + kc * 32);
        }
        b1v[nf] = b1[wr];
    }

    const int NT = (NN + 31) / 32;
    for (int tile = blockIdx.x; tile < NT; tile += gridDim.x) {
        const int n0t = tile * 32;
        int nn = NN - n0t; if (nn > 32) nn = 32;
        __syncthreads();
#pragma unroll
        for (int ii = 0; ii < 2; ii++) {
            int idx = t + ii * 256;
            int rr = idx >> 4, c = idx & 15;
            int node = n0t + ((rr < nn) ? rr : 0);
            a1s[rr * 16 + (c ^ (rr & 7))] =
                *(const uint4*)(hnb + (size_t)node * 128 + c * 8);
        }
        __syncthreads();

        f32x4 t00 = {0,0,0,0}, t01 = {0,0,0,0}, t10 = {0,0,0,0}, t11 = {0,0,0,0};
        f32x4 u00 = {0,0,0,0}, u01 = {0,0,0,0}, u10 = {0,0,0,0}, u11 = {0,0,0,0};
        {
            const bf16x8* A = (const bf16x8*)a1s;
#pragma unroll
            for (int kc = 0; kc < 4; kc++) {
                int ch = kc * 4 + g4;
                bf16x8 f0 = A[l15 * 16 + (ch ^ sw)];
                bf16x8 f1 = A[(l15 + 16) * 16 + (ch ^ sw)];
                t00 = __builtin_amdgcn_mfma_f32_16x16x32_bf16(f0, Btop[0][kc], t00, 0, 0, 0);
                t01 = __builtin_amdgcn_mfma_f32_16x16x32_bf16(f0, Btop[1][kc], t01, 0, 0, 0);
                t10 = __builtin_amdgcn_mfma_f32_16x16x32_bf16(f1, Btop[0][kc], t10, 0, 0, 0);
                t11 = __builtin_amdgcn_mfma_f32_16x16x32_bf16(f1, Btop[1][kc], t11, 0, 0, 0);
                u00 = __builtin_amdgcn_mfma_f32_16x16x32_bf16(f0, Bbot[0][kc], u00, 0, 0, 0);
                u01 = __builtin_amdgcn_mfma_f32_16x16x32_bf16(f0, Bbot[1][kc], u01, 0, 0, 0);
                u10 = __builtin_amdgcn_mfma_f32_16x16x32_bf16(f1, Bbot[0][kc], u10, 0, 0, 0);
                u11 = __builtin_amdgcn_mfma_f32_16x16x32_bf16(f1, Bbot[1][kc], u11, 0, 0, 0);
            }
        }
#pragma unroll
        for (int mf = 0; mf < 2; mf++) {
#pragma unroll
            for (int r = 0; r < 4; r++) {
                int row = mf * 16 + g4 * 4 + r;
                if (row < nn) {
                    int node = n0t + row;
#pragma unroll
                    for (int nf = 0; nf < 2; nf++) {
                        float tv = mf ? (nf ? t11[r] : t10[r]) : (nf ? t01[r] : t00[r]);
                        float uv = mf ? (nf ? u11[r] : u10[r]) : (nf ? u01[r] : u00[r]);
                        int col = n0 + nf * 16 + l15;
                        zrow[(size_t)node * 128 + col] = f2bf(tv + b1v[nf]);
                        zcol[(size_t)node * 128 + col] = f2bf(uv);
                    }
                }
            }
        }
    }
}

// ---------------- barrier-free per-wave edge kernel ----------------------
// 4 waves/block; each wave owns 16 edges per wave-tile, computes all 128
// features. Weights (w2T,cw1T) in chunk-swizzled LDS; per-wave 4KB LDS
// buffer for the C->A transpose. NO __syncthreads in the tile loop.
#define NWT (NE / 16)         // 37500
#define WT_PER_XCD 4688
#define WPW 10
__global__ __launch_bounds__(256, 2) void edge_kernel(
    const unsigned short* __restrict__ zrow,
    const unsigned short* __restrict__ zcol,
    const int* __restrict__ erow, const int* __restrict__ ecol,
    const int* __restrict__ perm,
    const float* __restrict__ coord, const float* __restrict__ w1,
    const float* __restrict__ b2, const float* __restrict__ eg,
    const float* __restrict__ ebias, const float* __restrict__ cb1,
    const float* __restrict__ cw2,
    const unsigned short* __restrict__ w2T,
    const unsigned short* __restrict__ cw1T,
    float* __restrict__ agg, float* __restrict__ svec) {
    __shared__ uint4 wlds[4096];      // 64KB: w2Ts [0..2047], cw1Ts [2048..]
    __shared__ uint4 ebuf4[4][256];   // 16KB: per-wave 16x128 bf16, swizzled

    const int t    = threadIdx.x;
    const int lane = t & 63;
    const int wave = t >> 6;
    const int l15  = lane & 15;
    const int g4   = lane >> 4;

    // block-coop weight staging into swizzled LDS
#pragma unroll
    for (int i = 0; i < 16; i++) {
        int gi = t + i * 256;
        int m = gi >> 11, rem = gi & 2047;
        int col = rem >> 4, c = rem & 15;
        const unsigned short* src = (m ? cw1T : w2T) + col * 128 + c * 8;
        wlds[m * 2048 + col * 16 + (c ^ (col & 15))] = *(const uint4*)src;
    }

    // per-lane preloads (feature col = ng*16 + l15)
    float b2v[8], egv[8], ebv[8], cb1v[8], cw2v[8];
#pragma unroll
    for (int ng = 0; ng < 8; ng++) {
        int col = ng * 16 + l15;
        b2v[ng]  = b2[col];  egv[ng]  = eg[col]; ebv[ng] = ebias[col];
        cb1v[ng] = cb1[col]; cw2v[ng] = cw2[col];
    }
    bf16x8 w1r8[4];                   // radial row of w1, frag per kc
#pragma unroll
    for (int kc = 0; kc < 4; kc++) {
        const float* p = w1 + 256 * 128 + kc * 32 + g4 * 8;
        bf16x8 v;
#pragma unroll
        for (int j = 0; j < 8; j++) v[j] = (short)f2bf(p[j]);
        w1r8[kc] = v;
    }
    __syncthreads();                  // the only block barrier

    const bf16x8* WB  = (const bf16x8*)wlds;
    unsigned short* EBu = (unsigned short*)(&ebuf4[wave][0]);
    const bf16x8*  EBc = (const bf16x8*)EBu;

    const int xcd   = blockIdx.x & 7;
    const int wslot = (blockIdx.x >> 3) * 4 + wave;
    int base = xcd * WT_PER_XCD;
    int cap  = base + WT_PER_XCD; if (cap > NWT) cap = NWT;
    int wt0  = base + wslot * WPW;
    int wt1  = wt0 + WPW; if (wt1 > cap) wt1 = cap;

    for (int wt = wt0; wt < wt1; wt++) {
        const int e0 = wt * 16;
        int eid = perm[e0 + l15];
        int rid = erow[eid], cid = ecol[eid];
        float dx = coord[rid * 3 + 0] - coord[cid * 3 + 0];
        float dy = coord[rid * 3 + 1] - coord[cid * 3 + 1];
        float dz = coord[rid * 3 + 2] - coord[cid * 3 + 2];
        float rad = dx * dx + dy * dy + dz * dz;

        // ---- form A2 frags directly: e1 = silu(zrow[rid]+zcol[cid]+rad*w1r)
        bf16x8 A2[4];
#pragma unroll
        for (int kc = 0; kc < 4; kc++) {
            bf16x8 zr = *(const bf16x8*)(zrow + (size_t)rid * 128 + kc * 32 + g4 * 8);
            bf16x8 zc = *(const bf16x8*)(zcol + (size_t)cid * 128 + kc * 32 + g4 * 8);
            bf16x8 o;
#pragma unroll
            for (int j = 0; j < 8; j++) {
                float x = bf2f((unsigned short)zr[j]) + bf2f((unsigned short)zc[j])
                        + rad * bf2f((unsigned short)w1r8[kc][j]);
                o[j] = (short)f2bf(silu_f(x));
            }
            A2[kc] = o;
        }
        // ---- GEMM2: e2 = e1 @ w2 (C: col=ng*16+l15, row=edge g4*4+r) ----
        f32x4 acc2[8];
#pragma unroll
        for (int ng = 0; ng < 8; ng++) {
            f32x4 a = {0, 0, 0, 0};
            int rowb = (ng * 16 + l15) * 16;
#pragma unroll
            for (int kc = 0; kc < 4; kc++)
                a = __builtin_amdgcn_mfma_f32_16x16x32_bf16(
                        A2[kc], WB[rowb + ((kc * 4 + g4) ^ l15)], a, 0, 0, 0);
            acc2[ng] = a;
        }
        // ---- bias + silu + in-register LayerNorm ----
#pragma unroll
        for (int r = 0; r < 4; r++) {
            float sp = 0.0f, sq = 0.0f;
#pragma unroll
            for (int ng = 0; ng < 8; ng++) {
                float v = silu_f(acc2[ng][r] + b2v[ng]);
                acc2[ng][r] = v; sp += v; sq += v * v;
            }
            sp += __shfl_xor(sp, 1); sq += __shfl_xor(sq, 1);
            sp += __shfl_xor(sp, 2); sq += __shfl_xor(sq, 2);
            sp += __shfl_xor(sp, 4); sq += __shfl_xor(sq, 4);
            sp += __shfl_xor(sp, 8); sq += __shfl_xor(sq, 8);
            float m  = sp * (1.0f / 128.0f);
            float va = sq * (1.0f / 128.0f) - m * m;
            float inv = rsqrtf(va + 1e-5f);
#pragma unroll
            for (int ng = 0; ng < 8; ng++)
                acc2[ng][r] = (acc2[ng][r] - m) * inv * egv[ng] + ebv[ng];
        }
        // ---- transpose e -> per-wave LDS (A-layout, chunk-swizzled) ----
#pragma unroll
        for (int r = 0; r < 4; r++) {
            int er = g4 * 4 + r;
#pragma unroll
            for (int ng = 0; ng < 8; ng++) {
                int pos = ((ng * 2 + (l15 >> 3)) ^ er) & 15;
                EBu[er * 128 + pos * 8 + (l15 & 7)] = f2bf(acc2[ng][r]);
            }
        }
        // ---- agg scatter, segment-combined over the r-dim ----
        {
            float accA[8];
#pragma unroll
            for (int ng = 0; ng < 8; ng++) accA[ng] = 0.0f;
            int curR = __shfl(rid, g4 * 4);
#pragma unroll
            for (int r = 0; r < 4; r++) {
                int rr = __shfl(rid, g4 * 4 + r);
                if (rr != curR) {
#pragma unroll
                    for (int ng = 0; ng < 8; ng++) {
                        atomicAdd(&agg[(size_t)curR * 128 + ng * 16 + l15], accA[ng]);
                        accA[ng] = 0.0f;
                    }
                    curR = rr;
                }
#pragma unroll
                for (int ng = 0; ng < 8; ng++) accA[ng] += acc2[ng][r];
            }
#pragma unroll
            for (int ng = 0; ng < 8; ng++)
                atomicAdd(&agg[(size_t)curR * 128 + ng * 16 + l15], accA[ng]);
        }
        // ---- GEMM3: P = e @ cw1 ----
        bf16x8 A3[4];
#pragma unroll
        for (int kc = 0; kc < 4; kc++)
            A3[kc] = EBc[l15 * 16 + ((kc * 4 + g4) ^ l15)];
        f32x4 acc3[8];
#pragma unroll
        for (int ng = 0; ng < 8; ng++) {
            f32x4 a = {0, 0, 0, 0};
            int rowb = 2048 + (ng * 16 + l15) * 16;
#pragma unroll
            for (int kc = 0; kc < 4; kc++)
                a = __builtin_amdgcn_mfma_f32_16x16x32_bf16(
                        A3[kc], WB[rowb + ((kc * 4 + g4) ^ l15)], a, 0, 0, 0);
            acc3[ng] = a;
        }
        // ---- scale = row-sum(silu(P+cb1)*cw2); svec scatter ----
#pragma unroll
        for (int r = 0; r < 4; r++) {
            float ps = 0.0f;
#pragma unroll
            for (int ng = 0; ng < 8; ng++)
                ps += silu_f(acc3[ng][r] + cb1v[ng]) * cw2v[ng];
            ps += __shfl_xor(ps, 1);
            ps += __shfl_xor(ps, 2);
            ps += __shfl_xor(ps, 4);
            ps += __shfl_xor(ps, 8);
            int er = g4 * 4 + r;
            int rr = __shfl(rid, er);
            float sx = __shfl(dx, er), sy = __shfl(dy, er), sz = __shfl(dz, er);
            if (l15 == 0)      atomicAdd(&svec[rr * 3 + 0], sx * ps);
            else if (l15 == 1) atomicAdd(&svec[rr * 3 + 1], sy * ps);
            else if (l15 == 2) atomicAdd(&svec[rr * 3 + 2], sz * ps);
        }
    }
}

// swizzled ushort index into a [rows][128] bf16 LDS tile (16B chunk XOR)
__device__ __forceinline__ int swz128(int row, int col) {
    return row * 128 + (((col >> 3) ^ (row & 7)) << 3) + (col & 7);
}

// ---------------- MFMA node kernel + coord_out ---------------------------
__global__ __launch_bounds__(256, 2) void node_kernel(
    const float* __restrict__ h, const unsigned short* __restrict__ hnb,
    const float* __restrict__ aggp, const float* __restrict__ coord,
    const float* __restrict__ nb1, const float* __restrict__ nb2,
    const unsigned short* __restrict__ nw1T,
    const unsigned short* __restrict__ nw2T,
    const float* __restrict__ svec, const int* __restrict__ bins,
    float* __restrict__ hout, float* __restrict__ cout) {
    __shared__ uint4 a1s[32 * 32];   // [32 nodes][256 k] bf16, swizzled
    __shared__ uint4 nbs[32 * 16];   // hidden [32][128] bf16

    const int t    = threadIdx.x;
    const int lane = t & 63;
    const int wave = t >> 6;
    const int l15  = lane & 15;
    const int g4   = lane >> 4;
    const int n0   = wave * 32;
    const int sw   = l15 & 7;

    bf16x8 B1[2][8], B2[2][4];
    float nb1v[2], nb2v[2];
#pragma unroll
    for (int nf = 0; nf < 2; nf++) {
        int wr = n0 + nf * 16 + l15;
        const unsigned short* p1 = nw1T + wr * 256 + g4 * 8;
#pragma unroll
        for (int kc = 0; kc < 8; kc++) B1[nf][kc] = *(const bf16x8*)(p1 + kc * 32);
        const unsigned short* p2 = nw2T + wr * 128 + g4 * 8;
#pragma unroll
        for (int kc = 0; kc < 4; kc++) B2[nf][kc] = *(const bf16x8*)(p2 + kc * 32);
        nb1v[nf] = nb1[wr]; nb2v[nf] = nb2[wr];
    }
    unsigned short* nbu = (unsigned short*)nbs;

    const int NT = (NN + 31) / 32;
    for (int tile = blockIdx.x; tile < NT; tile += gridDim.x) {
        const int n0t = tile * 32;
        int nn = NN - n0t; if (nn > 32) nn = 32;

        if (t < 96) {
            int i = t / 3, j = t - (t / 3) * 3;
            int node = n0t + i;
            if (i < nn) {
                float c = fmaxf((float)bins[node], 1.0f);
                cout[node * 3 + j] = coord[node * 3 + j] + svec[node * 3 + j] / c;
            }
        }
        __syncthreads();
#pragma unroll
        for (int ii = 0; ii < 4; ii++) {
            int idx = t + ii * 256;
            int rr = idx >> 5, c = idx & 31;
            int node = n0t + ((rr < nn) ? rr : 0);
            uint4 d;
            if (c < 16) {
                d = *(const uint4*)(hnb + (size_t)node * 128 + c * 8);
            } else {
                const float* ap = aggp + (size_t)node * 128 + (c - 16) * 8;
                float4 f0 = *(const float4*)ap;
                float4 f1 = *(const float4*)(ap + 4);
                d.x = f2bf(f0.x) | ((unsigned)f2bf(f0.y) << 16);
                d.y = f2bf(f0.z) | ((unsigned)f2bf(f0.w) << 16);
                d.z = f2bf(f1.x) | ((unsigned)f2bf(f1.y) << 16);
                d.w = f2bf(f1.z) | ((unsigned)f2bf(f1.w) << 16);
            }
            a1s[rr * 32 + (c ^ (rr & 7))] = d;
        }
        __syncthreads();

        f32x4 a00 = {0,0,0,0}, a01 = {0,0,0,0}, a10 = {0,0,0,0}, a11 = {0,0,0,0};
        {
            const bf16x8* A = (const bf16x8*)a1s;
#pragma unroll
            for (int kc = 0; kc < 8; kc++) {
                int ch = kc * 4 + g4;
                bf16x8 f0 = A[l15 * 32 + (ch ^ sw)];
                bf16x8 f1 = A[(l15 + 16) * 32 + (ch ^ sw)];
                a00 = __builtin_amdgcn_mfma_f32_16x16x32_bf16(f0, B1[0][kc], a00, 0, 0, 0);
                a01 = __builtin_amdgcn_mfma_f32_16x16x32_bf16(f0, B1[1][kc], a01, 0, 0, 0);
                a10 = __builtin_amdgcn_mfma_f32_16x16x32_bf16(f1, B1[0][kc], a10, 0, 0, 0);
                a11 = __builtin_amdgcn_mfma_f32_16x16x32_bf16(f1, B1[1][kc], a11, 0, 0, 0);
            }
        }
#pragma unroll
        for (int mf = 0; mf < 2; mf++) {
#pragma unroll
            for (int r = 0; r < 4; r++) {
                int row = mf * 16 + g4 * 4 + r;
#pragma unroll
                for (int nf = 0; nf < 2; nf++) {
                    float v = mf ? (nf ? a11[r] : a10[r]) : (nf ? a01[r] : a00[r]);
                    v = silu_f(v + nb1v[nf]);
                    int col = n0 + nf * 16 + l15;
                    nbu[swz128(row, col)] = f2bf(v);
                }
            }
        }
        __syncthreads();

        f32x4 c00 = {0,0,0,0}, c01 = {0,0,0,0}, c10 = {0,0,0,0}, c11 = {0,0,0,0};
        {
            const bf16x8* A = (const bf16x8*)nbs;
#pragma unroll
            for (int kc = 0; kc < 4; kc++) {
                int ch = kc * 4 + g4;
                bf16x8 f0 = A[l15 * 16 + (ch ^ sw)];
                bf16x8 f1 = A[(l15 + 16) * 16 + (ch ^ sw)];
                c00 = __builtin_amdgcn_mfma_f32_16x16x32_bf16(f0, B2[0][kc], c00, 0, 0, 0);
                c01 = __builtin_amdgcn_mfma_f32_16x16x32_bf16(f0, B2[1][kc], c01, 0, 0, 0);
                c10 = __builtin_amdgcn_mfma_f32_16x16x32_bf16(f1, B2[0][kc], c10, 0, 0, 0);
                c11 = __builtin_amdgcn_mfma_f32_16x16x32_bf16(f1, B2[1][kc], c11, 0, 0, 0);
            }
        }
#pragma unroll
        for (int mf = 0; mf < 2; mf++) {
#pragma unroll
            for (int r = 0; r < 4; r++) {
                int row = mf * 16 + g4 * 4 + r;
                if (row < nn) {
                    int node = n0t + row;
#pragma unroll
                    for (int nf = 0; nf < 2; nf++) {
                        float v = mf ? (nf ? c11[r] : c10[r]) : (nf ? c01[r] : c00[r]);
                        int col = n0 + nf * 16 + l15;
                        hout[(size_t)node * 128 + col] =
                            v + nb2v[nf] + h[(size_t)node * 128 + col];
                    }
                }
            }
        }
    }
}

extern "C" void kernel_launch(void* const* d_in, const int* in_sizes, int n_in,
                              void* d_out, int out_size, void* d_ws, size_t ws_size,
                              hipStream_t stream) {
    const float* h     = (const float*)d_in[0];
    const int*   eidx  = (const int*)d_in[1];
    const float* coord = (const float*)d_in[2];
    const float* nlg   = (const float*)d_in[3];
    const float* nlb   = (const float*)d_in[4];
    const float* elg   = (const float*)d_in[5];
    const float* elb   = (const float*)d_in[6];
    const float* ew1   = (const float*)d_in[7];
    const float* eb1   = (const float*)d_in[8];
    const float* ew2   = (const float*)d_in[9];
    const float* eb2   = (const float*)d_in[10];
    const float* nw1   = (const float*)d_in[11];
    const float* nb1   = (const float*)d_in[12];
    const float* nw2   = (const float*)d_in[13];
    const float* nb2   = (const float*)d_in[14];
    const float* cw1   = (const float*)d_in[15];
    const float* cb1   = (const float*)d_in[16];
    const float* cw2   = (const float*)d_in[17];

    float* hout = (float*)d_out;
    float* cout = (float*)d_out + (size_t)NN * 128;

    // ws layout (bytes, 16B-aligned):
    char* ws = (char*)d_ws;
    unsigned short* hnb  = (unsigned short*)(ws);             // 12,800,000
    float*          agg  = (float*)(ws + 12800000);           // 25,600,000
    float*          svec = (float*)(ws + 38400000);           //    600,000
    int*            bins = (int*)(ws + 39000000);             //    200,000
    int*            cur  = (int*)(ws + 39200000);             //    200,000
    int*            bsum = (int*)(ws + 39400000);             //      1,024
    int*            perm = (int*)(ws + 39401024);             //  2,400,000
    unsigned short* w1T  = (unsigned short*)(ws + 41801024);  //     65,536
    unsigned short* w2T  = (unsigned short*)(ws + 41866560);  //     32,768
    unsigned short* cw1T = (unsigned short*)(ws + 41899328);  //     32,768
    unsigned short* nw1T = (unsigned short*)(ws + 41932096);  //     65,536
    unsigned short* nw2T = (unsigned short*)(ws + 41997632);  //     32,768
    unsigned short* zrow = (unsigned short*)(ws + 42030400);  // 12,800,000
    unsigned short* zcol = (unsigned short*)(ws + 54830400);  // 12,800,000

    // zero agg|svec|bins (contiguous region)
    hipMemsetAsync(agg, 0, (size_t)25600000 + 600000 + 200000, stream);

    const int* erow = eidx;
    const int* ecol = eidx + NE;

    const int NB = (NN + 255) / 256;   // 196

    hist_kernel<<<(NE + 255) / 256, 256, 0, stream>>>(erow, bins);
    scan1_kernel<<<NB, 256, 0, stream>>>(bins, bsum);
    scan2_kernel<<<1, 64, 0, stream>>>(bsum, NB);
    scan3_kernel<<<NB, 256, 0, stream>>>(bins, bsum, cur);
    scatter_kernel<<<(NE + 255) / 256, 256, 0, stream>>>(erow, cur, perm);

    prep_weights<<<448, 256, 0, stream>>>(ew1, ew2, cw1, nw1, nw2,
                                          w1T, w2T, cw1T, nw1T, nw2T);
    ln_nodes_kernel<<<(NN + 3) / 4, 256, 0, stream>>>(h, nlg, nlb, hnb);
    z_kernel<<<512, 256, 0, stream>>>(hnb, w1T, eb1, zrow, zcol);
    edge_kernel<<<1024, 256, 0, stream>>>(
        zrow, zcol, erow, ecol, perm, coord, ew1, eb2, elg, elb, cb1, cw2,
        w2T, cw1T, agg, svec);
    node_kernel<<<512, 256, 0, stream>>>(
        h, hnb, agg, coord, nb1, nb2, nw1T, nw2T, svec, bins, hout, cout);
}